// Round 8
// baseline (204.351 us; speedup 1.0000x reference)
//
#include <hip/hip_runtime.h>
#include <hip/hip_fp16.h>

// Problem constants (fixed by the reference setup)
#define NB 8
#define KF 16
#define HW 65536                // 256*256
#define NPIX (NB * HW)          // 524288
#define NPTS 100000
#define NCH 4

// Workspace layout (ws is ~268MB, poisoned 0xAA each replay)
#define WS_TABLE_OFF 0                    // 800KB fp16x4 table
#define WS_NG_OFF    (32u << 20)          // nogather ablation output (2.1MB)
#define WS_FO_OFF    (64u << 20)          // fragonly ablation output (2.1MB)
#define WS_MIN_BYTES ((64u << 20) + (NPIX + 16) * sizeof(float))

// ---------------------------------------------------------------------------
// Kernel 1: transpose + pack ptclds (C,P) f32 -> (P) 4xfp16 (8B per point).
// ---------------------------------------------------------------------------
__global__ void ptclds_pack_kernel(const float* __restrict__ pt,
                                   uint2* __restrict__ ws) {
    int p = blockIdx.x * blockDim.x + threadIdx.x;
    if (p < NPTS) {
        __half2 h01 = __floats2half2_rn(pt[p],            pt[NPTS + p]);
        __half2 h23 = __floats2half2_rn(pt[2 * NPTS + p], pt[3 * NPTS + p]);
        uint2 q;
        q.x = *reinterpret_cast<unsigned int*>(&h01);
        q.y = *reinterpret_cast<unsigned int*>(&h23);
        ws[p] = q;
    }
}

// ---------------------------------------------------------------------------
// Kernel 2 (SHIPPING, unchanged R6): branchless, 1 px/thread, fp16x4 gather.
// ---------------------------------------------------------------------------
__global__ __launch_bounds__(256, 6) void composite_kernel(
    const int* __restrict__ frags, const float* __restrict__ alphas,
    const uint2* __restrict__ ws, const float* __restrict__ bg,
    float* __restrict__ out)
{
    int i = blockIdx.x * blockDim.x + threadIdx.x;
    if (i >= NPIX) return;
    int n  = i >> 16;
    int hw = i & (HW - 1);
    long base = (long)n * KF * HW + hw;

    int f[KF];
    float a[KF];
    #pragma unroll
    for (int k = 0; k < KF; ++k) f[k] = frags[base + (long)k * HW];
    #pragma unroll
    for (int k = 0; k < KF; ++k) a[k] = alphas[base + (long)k * HW];

    float4 acc = make_float4(0.f, 0.f, 0.f, 0.f);
    float T = 1.0f;
    #pragma unroll
    for (int k = 0; k < KF; ++k) {
        const bool v = f[k] >= 0;
        const int idx = v ? f[k] : 0;
        const uint2 q = ws[idx];
        const __half2 h01 = *reinterpret_cast<const __half2*>(&q.x);
        const __half2 h23 = *reinterpret_cast<const __half2*>(&q.y);
        const float2 g01 = __half22float2(h01);
        const float2 g23 = __half22float2(h23);
        const float av = v ? a[k] : 0.f;
        const float w = av * T;
        acc.x += w * g01.x;
        acc.y += w * g01.y;
        acc.z += w * g23.x;
        acc.w += w * g23.y;
        T *= (1.0f - av);
    }
    if (f[0] < 0) acc = make_float4(bg[0], bg[1], bg[2], 1.0f);

    long ob = (long)n * NCH * HW + hw;
    out[ob]          = acc.x;
    out[ob + HW]     = acc.y;
    out[ob + 2 * HW] = acc.z;
    out[ob + 3 * HW] = acc.w;
}

// ---------------------------------------------------------------------------
// ABLATION A: identical streams + weight math, NO gather (g = constants).
// 6 reps so it ranks above the 41us poison fills in rocprof top-5.
// ---------------------------------------------------------------------------
__global__ __launch_bounds__(256, 6) void k_nogather(
    const int* __restrict__ frags, const float* __restrict__ alphas,
    float* __restrict__ wsout)
{
    int i0 = blockIdx.x * blockDim.x + threadIdx.x;
    if (i0 >= NPIX) return;
    #pragma unroll 1
    for (int rep = 0; rep < 6; ++rep) {
        int i = i0;
        asm volatile("" : "+v"(i));   // opaque: defeat cross-rep load CSE
        int n  = i >> 16;
        int hw = i & (HW - 1);
        long base = (long)n * KF * HW + hw;

        int f[KF];
        float a[KF];
        #pragma unroll
        for (int k = 0; k < KF; ++k) f[k] = frags[base + (long)k * HW];
        #pragma unroll
        for (int k = 0; k < KF; ++k) a[k] = alphas[base + (long)k * HW];

        float4 acc = make_float4(0.f, 0.f, 0.f, 0.f);
        float T = 1.0f;
        #pragma unroll
        for (int k = 0; k < KF; ++k) {
            const bool v = f[k] >= 0;
            const float av = v ? a[k] : 0.f;
            const float w = av * T;
            acc.x += w * 1.0f;
            acc.y += w * 0.5f;
            acc.z += w * 0.25f;
            acc.w += w * 2.0f;
            T *= (1.0f - av);
        }
        wsout[i0] = acc.x + acc.y + acc.z + acc.w + T;
    }
}

// ---------------------------------------------------------------------------
// ABLATION B: frags stream + IDENTICAL gather pattern, no alpha read
// (const alpha 0.5 for valid). 3 reps.
// ---------------------------------------------------------------------------
__global__ __launch_bounds__(256, 6) void k_fragonly(
    const int* __restrict__ frags, const uint2* __restrict__ ws,
    float* __restrict__ wsout)
{
    int i0 = blockIdx.x * blockDim.x + threadIdx.x;
    if (i0 >= NPIX) return;
    #pragma unroll 1
    for (int rep = 0; rep < 3; ++rep) {
        int i = i0;
        asm volatile("" : "+v"(i));   // opaque: defeat cross-rep load CSE
        int n  = i >> 16;
        int hw = i & (HW - 1);
        long base = (long)n * KF * HW + hw;

        int f[KF];
        #pragma unroll
        for (int k = 0; k < KF; ++k) f[k] = frags[base + (long)k * HW];

        float4 acc = make_float4(0.f, 0.f, 0.f, 0.f);
        float T = 1.0f;
        #pragma unroll
        for (int k = 0; k < KF; ++k) {
            const bool v = f[k] >= 0;
            const int idx = v ? f[k] : 0;
            const uint2 q = ws[idx];
            const __half2 h01 = *reinterpret_cast<const __half2*>(&q.x);
            const __half2 h23 = *reinterpret_cast<const __half2*>(&q.y);
            const float2 g01 = __half22float2(h01);
            const float2 g23 = __half22float2(h23);
            const float av = v ? 0.5f : 0.f;
            const float w = av * T;
            acc.x += w * g01.x;
            acc.y += w * g01.y;
            acc.z += w * g23.x;
            acc.w += w * g23.y;
            T *= (1.0f - av);
        }
        wsout[i0] = acc.x + acc.y + acc.z + acc.w + T;
    }
}

extern "C" void kernel_launch(void* const* d_in, const int* in_sizes, int n_in,
                              void* d_out, int out_size, void* d_ws, size_t ws_size,
                              hipStream_t stream) {
    const int*   frags  = (const int*)d_in[0];
    const float* alphas = (const float*)d_in[1];
    const float* pt     = (const float*)d_in[2];
    const float* bg     = (const float*)d_in[3];
    float* out = (float*)d_out;

    char* wsb = (char*)d_ws;
    uint2* table = (uint2*)(wsb + WS_TABLE_OFF);

    ptclds_pack_kernel<<<(NPTS + 255) / 256, 256, 0, stream>>>(pt, table);
    composite_kernel<<<NPIX / 256, 256, 0, stream>>>(frags, alphas, table, bg, out);

    if (ws_size >= WS_MIN_BYTES) {
        float* ng_out = (float*)(wsb + WS_NG_OFF);
        float* fo_out = (float*)(wsb + WS_FO_OFF);
        k_nogather<<<NPIX / 256, 256, 0, stream>>>(frags, alphas, ng_out);
        k_fragonly<<<NPIX / 256, 256, 0, stream>>>(frags, table, fo_out);
    }
}

// Round 10
// 117.331 us; speedup vs baseline: 1.7417x; 1.7417x over previous
//
#include <hip/hip_runtime.h>
#include <hip/hip_fp16.h>

// Problem constants (fixed by the reference setup)
#define NB 8
#define KF 16
#define HW 65536                // 256*256
#define NPIX (NB * HW)          // 524288
#define NPTS 100000
#define NCH 4

// ---------------------------------------------------------------------------
// Kernel 1: transpose + pack ptclds (C,P) f32 -> (P) 4xfp16 (8B per point).
// fp16 error <= 2^-12/feature, weights sum <= 1 -> absmax impact ~3e-4
// (threshold 2e-2). 800KB table is L2-resident per XCD.
// ---------------------------------------------------------------------------
__global__ void ptclds_pack_kernel(const float* __restrict__ pt,
                                   uint2* __restrict__ ws) {
    int p = blockIdx.x * blockDim.x + threadIdx.x;
    if (p < NPTS) {
        __half2 h01 = __floats2half2_rn(pt[p],            pt[NPTS + p]);
        __half2 h23 = __floats2half2_rn(pt[2 * NPTS + p], pt[3 * NPTS + p]);
        uint2 q;
        q.x = *reinterpret_cast<unsigned int*>(&h01);
        q.y = *reinterpret_cast<unsigned int*>(&h23);
        ws[p] = q;
    }
}

// ---------------------------------------------------------------------------
// Kernel 2: branchless compositing, 1 pixel/thread, LEAN-VGPR version.
// R8 ablations showed fragonly (32 VGPR, 51% occ) overlaps gather service
// with streams, while the 76-VGPR staged composite does not. Changes vs R6:
//   - only frags staged in registers (feeds gather MLP);
//   - alphas loaded in-loop (coalesced, compiler-pipelined);
//   - __launch_bounds__(256, 8) caps VGPR at 64 -> 8 waves/SIMD.
// NO nontemporal builtins (R3 lesson: nt ops race the 0xAA poison fill).
// ---------------------------------------------------------------------------
template <bool PACKED>
__global__ __launch_bounds__(256, 8) void composite_kernel(
    const int* __restrict__ frags,     // (N,K,H,W)
    const float* __restrict__ alphas,  // (N,K,H,W)
    const float* __restrict__ pt,      // (C,P)  (used when !PACKED)
    const uint2* __restrict__ ws,      // (P) 4xfp16 (used when PACKED)
    const float* __restrict__ bg,      // (3,)
    float* __restrict__ out)           // (N,C,H,W)
{
    int i = blockIdx.x * blockDim.x + threadIdx.x;
    if (i >= NPIX) return;

    const int n  = i >> 16;          // i / HW
    const int hw = i & (HW - 1);     // i % HW

    const long base = (long)n * KF * HW + hw;
    const int*   fp = frags  + base;
    const float* ap = alphas + base;

    // Stage fragment indices only: 16 independent coalesced loads -> gather MLP.
    int f[KF];
    #pragma unroll
    for (int k = 0; k < KF; ++k) f[k] = fp[(long)k * HW];

    float4 acc = make_float4(0.f, 0.f, 0.f, 0.f);
    float T = 1.0f;

    #pragma unroll
    for (int k = 0; k < KF; ++k) {
        const float a = ap[(long)k * HW];   // in-loop: no register staging
        const bool v = f[k] >= 0;
        const int idx = v ? f[k] : 0;       // invalid -> broadcast line 0
        float4 g;
        if (PACKED) {
            const uint2 q = ws[idx];
            const __half2 h01 = *reinterpret_cast<const __half2*>(&q.x);
            const __half2 h23 = *reinterpret_cast<const __half2*>(&q.y);
            const float2 g01 = __half22float2(h01);
            const float2 g23 = __half22float2(h23);
            g = make_float4(g01.x, g01.y, g23.x, g23.y);
        } else {
            g = make_float4(pt[idx], pt[NPTS + idx],
                            pt[2 * NPTS + idx], pt[3 * NPTS + idx]);
        }
        const float av = v ? a : 0.f;
        const float w = av * T;
        acc.x += w * g.x;
        acc.y += w * g.y;
        acc.z += w * g.z;
        acc.w += w * g.w;
        T *= (1.0f - av);
    }

    // Background fill where no nearest point exists.
    if (f[0] < 0) acc = make_float4(bg[0], bg[1], bg[2], 1.0f);

    const long ob = (long)n * NCH * HW + hw;
    out[ob]          = acc.x;
    out[ob + HW]     = acc.y;
    out[ob + 2 * HW] = acc.z;
    out[ob + 3 * HW] = acc.w;
}

extern "C" void kernel_launch(void* const* d_in, const int* in_sizes, int n_in,
                              void* d_out, int out_size, void* d_ws, size_t ws_size,
                              hipStream_t stream) {
    const int*   frags  = (const int*)d_in[0];    // fragments (N,K,H,W) int32
    const float* alphas = (const float*)d_in[1];  // alphas    (N,K,H,W) f32
    const float* pt     = (const float*)d_in[2];  // ptclds    (C,P)     f32
    const float* bg     = (const float*)d_in[3];  // background_color (3,) f32
    float* out = (float*)d_out;                   // (N,C,H,W) f32

    const bool packed = (ws_size >= (size_t)NPTS * sizeof(uint2));

    if (packed) {
        uint2* ws = (uint2*)d_ws;
        ptclds_pack_kernel<<<(NPTS + 255) / 256, 256, 0, stream>>>(pt, ws);
        composite_kernel<true><<<NPIX / 256, 256, 0, stream>>>(
            frags, alphas, pt, ws, bg, out);
    } else {
        composite_kernel<false><<<NPIX / 256, 256, 0, stream>>>(
            frags, alphas, pt, (const uint2*)nullptr, bg, out);
    }
}